// Round 9
// baseline (870.867 us; speedup 1.0000x reference)
//
#include <hip/hip_runtime.h>

#define N      12000
#define NHID   32
#define NCLASS 16

#define YCH    15                 // j-chunks (partial buffers)
#define TJ     40                 // j per LDS tile
#define NTILE  5                  // tiles per wave  (wave strip = 200 j)
#define JBLK   (4 * NTILE * TJ)   // 800 j per block; YCH*JBLK == N
#define RPB    64                 // rows per block (lane = row)
#define GX     ((N + RPB - 1) / RPB)   // 188

// ---------------------------------------------------------------------------
// k_support: sup = x @ (gcW @ fcW).  Each block redundantly computes the
// folded 32x16 weight Wc in LDS (16K FLOP, gcW/fcW L2-resident) — folding
// the weights BEFORE the big stream halves the 576 MB adj GEMV's work, and
// fusing the fold here removes a 1-block kernel + its dependency bubble.
// Block 0 also writes bc = gc_b @ fcW + fcb for k_final.
// ---------------------------------------------------------------------------
__global__ __launch_bounds__(256) void k_support(const float* __restrict__ x,
                                                 const float* __restrict__ gcW,
                                                 const float* __restrict__ gcb,
                                                 const float* __restrict__ fcW,
                                                 const float* __restrict__ fcb,
                                                 float* __restrict__ sup,
                                                 float* __restrict__ bc) {
    __shared__ float WcS[NHID * NCLASS];
    const int t = threadIdx.x;
    // 256 threads, 512 Wc entries -> 2 per thread
#pragma unroll
    for (int e = 0; e < 2; ++e) {
        const int idx = t + e * 256;
        const int m = idx >> 4, c = idx & 15;
        float s = 0.f;
#pragma unroll
        for (int k = 0; k < NHID; ++k) s += gcW[m * NHID + k] * fcW[k * NCLASS + c];
        WcS[idx] = s;
    }
    if (blockIdx.x == 0 && t < NCLASS) {
        float s = fcb[t];
#pragma unroll
        for (int k = 0; k < NHID; ++k) s += gcb[k] * fcW[k * NCLASS + t];
        bc[t] = s;
    }
    __syncthreads();

    const int row = blockIdx.x * 256 + t;
    if (row >= N) return;
    float xv[NHID];
#pragma unroll
    for (int q = 0; q < 8; ++q) {
        float4 v = *(const float4*)(x + (size_t)row * NHID + q * 4);
        xv[q * 4 + 0] = v.x; xv[q * 4 + 1] = v.y;
        xv[q * 4 + 2] = v.z; xv[q * 4 + 3] = v.w;
    }
    float acc[NCLASS];
#pragma unroll
    for (int c = 0; c < NCLASS; ++c) acc[c] = 0.f;
#pragma unroll 8
    for (int m = 0; m < NHID; ++m) {
        const float xm = xv[m];
        const float* w = &WcS[m * NCLASS];
#pragma unroll
        for (int c = 0; c < NCLASS; ++c) acc[c] += xm * w[c];
    }
#pragma unroll
    for (int q = 0; q < 4; ++q)
        *(float4*)(sup + (size_t)row * NCLASS + q * 4) =
            make_float4(acc[q * 4], acc[q * 4 + 1], acc[q * 4 + 2], acc[q * 4 + 3]);
}

// ---------------------------------------------------------------------------
// k_gemv: the 576 MB stream.  partial[y] (or h, atomics) += adj[:, jchunk] @ sup
// grid (188, 15), block 256 = 4 waves; each wave owns 64 rows x 200-j strip
// (5 tiles of 40 j), private LDS tile [64][41] (stride 41: column read bank =
// (9*lane + j) mod 32, gcd(9,32)=1 -> conflict-free; 2-way wave64 aliasing is
// free per m136). sup row is wave-uniform -> readfirstlane base -> scalar
// broadcast loads. Per j-step: 1 ds_read_b32 + 16 v_fmac_f32.
// WAR on tile overwrite is safe without explicit waitcnt: per-wave DS ops
// execute in order, and the compiler orders the write after the read (same
// array). Roofline: need 10.3 B/cy/CU at 6.3 TB/s; VALU-paced supply
// ~28 B/cy/CU -> memory-bound, VALUBusy ~35%.
// ---------------------------------------------------------------------------
template <bool PART>
__global__ __launch_bounds__(256, 3) void k_gemv(const float* __restrict__ adj,
                                                 const float* __restrict__ sup,
                                                 float* __restrict__ dst) {
    __shared__ float lds[4 * RPB * (TJ + 1)];      // 41984 B -> 3 blocks/CU
    const int lane = threadIdx.x & 63;
    const int wid  = threadIdx.x >> 6;
    const int row0 = blockIdx.x * RPB;
    const int jbase = blockIdx.y * JBLK + wid * (NTILE * TJ);
    float* myTile = &lds[wid * (RPB * (TJ + 1))];

    float acc[NCLASS];
#pragma unroll
    for (int c = 0; c < NCLASS; ++c) acc[c] = 0.f;

    // prefetch tile 0: 640 float4 = 64 rows x 10 float4 (160 B contiguous/row)
    float4 pref[10];
#pragma unroll
    for (int s = 0; s < 10; ++s) {
        int flat = s * 64 + lane;
        int r = flat / 10, f4 = flat - r * 10;
        int row = row0 + r;
        pref[s] = make_float4(0.f, 0.f, 0.f, 0.f);
        if (row < N)
            pref[s] = *(const float4*)(adj + (size_t)row * N + (jbase + f4 * 4));
    }

    for (int tt = 0; tt < NTILE; ++tt) {
#pragma unroll
        for (int s = 0; s < 10; ++s) {
            int flat = s * 64 + lane;
            int r = flat / 10, f4 = flat - r * 10;
            float* d = &myTile[r * (TJ + 1) + f4 * 4];
            d[0] = pref[s].x; d[1] = pref[s].y; d[2] = pref[s].z; d[3] = pref[s].w;
        }
        if (tt < NTILE - 1) {   // issue next tile's loads; fly under compute
#pragma unroll
            for (int s = 0; s < 10; ++s) {
                int flat = s * 64 + lane;
                int r = flat / 10, f4 = flat - r * 10;
                int row = row0 + r;
                pref[s] = make_float4(0.f, 0.f, 0.f, 0.f);
                if (row < N)
                    pref[s] = *(const float4*)(adj + (size_t)row * N +
                                               (jbase + (tt + 1) * TJ + f4 * 4));
            }
        }
        const int jg0 = jbase + tt * TJ;
        // wave-uniform support base -> SGPR -> scalar broadcast loads
        const float* srow = sup + (size_t)__builtin_amdgcn_readfirstlane(jg0) * NCLASS;
        const float* base = &myTile[lane * (TJ + 1)];
#pragma unroll 8
        for (int j = 0; j < TJ; ++j) {
            const float a = base[j];                       // ds_read_b32, no conflict
            const float4* s4 = (const float4*)(srow + j * NCLASS);
            float4 s0 = s4[0], s1 = s4[1], s2 = s4[2], s3 = s4[3];
            acc[0]  += a * s0.x;  acc[1]  += a * s0.y;
            acc[2]  += a * s0.z;  acc[3]  += a * s0.w;
            acc[4]  += a * s1.x;  acc[5]  += a * s1.y;
            acc[6]  += a * s1.z;  acc[7]  += a * s1.w;
            acc[8]  += a * s2.x;  acc[9]  += a * s2.y;
            acc[10] += a * s2.z;  acc[11] += a * s2.w;
            acc[12] += a * s3.x;  acc[13] += a * s3.y;
            acc[14] += a * s3.z;  acc[15] += a * s3.w;
        }
    }

    // ---- block reduction: 4 waves (same rows, disjoint j) -> one write/row
    __syncthreads();
    float* red = lds;                              // overlay [4][64][17]
#pragma unroll
    for (int c = 0; c < NCLASS; ++c)
        red[(wid * 64 + lane) * 17 + c] = acc[c];
    __syncthreads();
    const int t = threadIdx.x;
    const int rrow = t >> 2;                       // 0..63
    const int kb = (t & 3) * 4;                    // float4 within the 16 outputs
    const int row = row0 + rrow;
    if (row < N) {
        float4 s;
        s.x = red[(0 * 64 + rrow) * 17 + kb + 0] + red[(1 * 64 + rrow) * 17 + kb + 0] +
              red[(2 * 64 + rrow) * 17 + kb + 0] + red[(3 * 64 + rrow) * 17 + kb + 0];
        s.y = red[(0 * 64 + rrow) * 17 + kb + 1] + red[(1 * 64 + rrow) * 17 + kb + 1] +
              red[(2 * 64 + rrow) * 17 + kb + 1] + red[(3 * 64 + rrow) * 17 + kb + 1];
        s.z = red[(0 * 64 + rrow) * 17 + kb + 2] + red[(1 * 64 + rrow) * 17 + kb + 2] +
              red[(2 * 64 + rrow) * 17 + kb + 2] + red[(3 * 64 + rrow) * 17 + kb + 2];
        s.w = red[(0 * 64 + rrow) * 17 + kb + 3] + red[(1 * 64 + rrow) * 17 + kb + 3] +
              red[(2 * 64 + rrow) * 17 + kb + 3] + red[(3 * 64 + rrow) * 17 + kb + 3];
        if (PART) {
            *(float4*)(dst + ((size_t)blockIdx.y * N + row) * NCLASS + kb) = s;
        } else {
            float* p = dst + (size_t)row * NCLASS + kb;
            atomicAdd(p + 0, s.x); atomicAdd(p + 1, s.y);
            atomicAdd(p + 2, s.z); atomicAdd(p + 3, s.w);
        }
    }
}

// ---------------------------------------------------------------------------
// k_final: out = sum_y part[y] + bc     (one float4 per thread, coalesced)
// ---------------------------------------------------------------------------
__global__ __launch_bounds__(256) void k_final(const float* __restrict__ part,
                                               const float* __restrict__ bc,
                                               float* __restrict__ out) {
    const int t = blockIdx.x * 256 + threadIdx.x;
    const int nf4 = N * NCLASS / 4;
    if (t >= nf4) return;
    float4 s = ((const float4*)bc)[t & 3];
#pragma unroll
    for (int p = 0; p < YCH; ++p) {
        float4 v = ((const float4*)part)[(size_t)p * nf4 + t];
        s.x += v.x; s.y += v.y; s.z += v.z; s.w += v.w;
    }
    ((float4*)out)[t] = s;
}

// k_bias (atomic fallback epilogue): out = h + bc
__global__ __launch_bounds__(256) void k_bias(const float* __restrict__ h,
                                              const float* __restrict__ bc,
                                              float* __restrict__ out) {
    const int t = blockIdx.x * 256 + threadIdx.x;
    const int nf4 = N * NCLASS / 4;
    if (t >= nf4) return;
    float4 v = ((const float4*)h)[t];
    float4 b = ((const float4*)bc)[t & 3];
    ((float4*)out)[t] = make_float4(v.x + b.x, v.y + b.y, v.z + b.z, v.w + b.w);
}

// ---------------------------------------------------------------------------
extern "C" void kernel_launch(void* const* d_in, const int* in_sizes, int n_in,
                              void* d_out, int out_size, void* d_ws, size_t ws_size,
                              hipStream_t stream) {
    const float* x   = (const float*)d_in[0];
    const float* adj = (const float*)d_in[1];
    const float* gcW = (const float*)d_in[2];
    const float* gcb = (const float*)d_in[3];
    const float* fcW = (const float*)d_in[4];
    const float* fcb = (const float*)d_in[5];
    float* out = (float*)d_out;

    float* bc  = (float*)d_ws;                         // [16]
    float* sup = bc + NCLASS;                          // [N][16], 16B-aligned
    float* big = sup + (size_t)N * NCLASS;             // partials OR h

    const size_t head = (size_t)(NCLASS + N * NCLASS) * sizeof(float);
    const size_t need_part = head + (size_t)YCH * N * NCLASS * sizeof(float);
    const size_t need_atom = head + (size_t)N * NCLASS * sizeof(float);
    if (ws_size < need_atom) return;   // refuse to write OOB (constant -> graph-safe)
    const bool use_part = ws_size >= need_part;        // constant per-run -> graph-safe

    k_support<<<(N + 255) / 256, 256, 0, stream>>>(x, gcW, gcb, fcW, fcb, sup, bc);

    const int nf4_blocks = (N * NCLASS / 4 + 255) / 256;
    if (use_part) {
        k_gemv<true><<<dim3(GX, YCH), 256, 0, stream>>>(adj, sup, big);
        k_final<<<nf4_blocks, 256, 0, stream>>>(big, bc, out);
    } else {
        hipMemsetAsync(big, 0, (size_t)N * NCLASS * sizeof(float), stream);
        k_gemv<false><<<dim3(GX, YCH), 256, 0, stream>>>(adj, sup, big);
        k_bias<<<nf4_blocks, 256, 0, stream>>>(big, bc, out);
    }
}